// Round 1
// baseline (530.246 us; speedup 1.0000x reference)
//
#include <hip/hip_runtime.h>
#include <math.h>

#define NPTS 2048
#define NB   16

// ---------------------------------------------------------------------------
// K1: x[16,2048,3] -> enc[16,2048,12]
//   h1 = fc1(x); bn1 (stats per n over (b,c), 96 elems); relu
//   h2 = fc2(a1); bn2 (192 elems); relu
//   enc = sigmoid(fc3(a2))
// One thread per n; serial loop over b; stats via recompute passes.
// ---------------------------------------------------------------------------
__global__ __launch_bounds__(256) void k1_encode(
    const float* __restrict__ x,
    const float* __restrict__ fc1_w, const float* __restrict__ fc1_b,
    const float* __restrict__ bn1_g, const float* __restrict__ bn1_b,
    const float* __restrict__ fc2_w, const float* __restrict__ fc2_b,
    const float* __restrict__ bn2_g, const float* __restrict__ bn2_b,
    const float* __restrict__ fc3_w, const float* __restrict__ fc3_b,
    float* __restrict__ enc)
{
    __shared__ float w1[18], b1[6], w2[72], b2[12], w3[144], b3[12];
    const int tid = threadIdx.x;
    if (tid < 18)  w1[tid] = fc1_w[tid];
    if (tid < 6)   b1[tid] = fc1_b[tid];
    if (tid < 72)  w2[tid] = fc2_w[tid];
    if (tid < 12)  { b2[tid] = fc2_b[tid]; b3[tid] = fc3_b[tid]; }
    if (tid < 144) w3[tid] = fc3_w[tid];
    __syncthreads();

    const int n = blockIdx.x * 256 + tid;
    const float g1 = bn1_g[n], e1 = bn1_b[n];
    const float g2 = bn2_g[n], e2 = bn2_b[n];

    // ---- pass A: bn1 stats (mean/var over b,c : 96 values)
    float s1 = 0.f, q1 = 0.f;
    for (int b = 0; b < NB; ++b) {
        const float* xp = x + (b * NPTS + n) * 3;
        const float x0 = xp[0], x1 = xp[1], x2 = xp[2];
#pragma unroll
        for (int c = 0; c < 6; ++c) {
            float h = fmaf(w1[c*3+0], x0, fmaf(w1[c*3+1], x1, fmaf(w1[c*3+2], x2, b1[c])));
            s1 += h; q1 = fmaf(h, h, q1);
        }
    }
    const float m1 = s1 * (1.f/96.f);
    const float i1 = 1.f / sqrtf(q1*(1.f/96.f) - m1*m1 + 1e-5f);

    // ---- pass B: bn2 stats (192 values)
    float s2 = 0.f, q2 = 0.f;
    for (int b = 0; b < NB; ++b) {
        const float* xp = x + (b * NPTS + n) * 3;
        const float x0 = xp[0], x1 = xp[1], x2 = xp[2];
        float a1[6];
#pragma unroll
        for (int c = 0; c < 6; ++c) {
            float h = fmaf(w1[c*3+0], x0, fmaf(w1[c*3+1], x1, fmaf(w1[c*3+2], x2, b1[c])));
            a1[c] = fmaxf((h - m1) * i1 * g1 + e1, 0.f);
        }
#pragma unroll
        for (int c = 0; c < 12; ++c) {
            float h = b2[c];
#pragma unroll
            for (int d = 0; d < 6; ++d) h = fmaf(w2[c*6+d], a1[d], h);
            s2 += h; q2 = fmaf(h, h, q2);
        }
    }
    const float m2 = s2 * (1.f/192.f);
    const float i2 = 1.f / sqrtf(q2*(1.f/192.f) - m2*m2 + 1e-5f);

    // ---- pass C: full chain -> enc
    for (int b = 0; b < NB; ++b) {
        const float* xp = x + (b * NPTS + n) * 3;
        const float x0 = xp[0], x1 = xp[1], x2 = xp[2];
        float a1[6];
#pragma unroll
        for (int c = 0; c < 6; ++c) {
            float h = fmaf(w1[c*3+0], x0, fmaf(w1[c*3+1], x1, fmaf(w1[c*3+2], x2, b1[c])));
            a1[c] = fmaxf((h - m1) * i1 * g1 + e1, 0.f);
        }
        float a2[12];
#pragma unroll
        for (int c = 0; c < 12; ++c) {
            float h = b2[c];
#pragma unroll
            for (int d = 0; d < 6; ++d) h = fmaf(w2[c*6+d], a1[d], h);
            a2[c] = fmaxf((h - m2) * i2 * g2 + e2, 0.f);
        }
        float* ep = enc + (b * NPTS + n) * 12;
#pragma unroll
        for (int c = 0; c < 12; ++c) {
            float h = b3[c];
#pragma unroll
            for (int d = 0; d < 12; ++d) h = fmaf(w3[c*12+d], a2[d], h);
            ep[c] = 1.f / (1.f + expf(-h));
        }
    }
}

// ---------------------------------------------------------------------------
// K2: 4x relmod fused, in place on xb[16,2048,12]. One block per batch.
//   f_i = wr*s*( x_i·(X^T U) - ||x_i||^2 u_i )/N + x_i ,  U = relu(X Wu^T + bu)
// Uses associativity (X X^T)U = X (X^T U): O(N D^2) instead of O(N^2 D).
// ---------------------------------------------------------------------------
__global__ __launch_bounds__(256) void k2_relmod(
    float* __restrict__ xb,
    const float* __restrict__ u1_w, const float* __restrict__ u1_b,
    const float* __restrict__ ps1, const float* __restrict__ ph1, const float* __restrict__ wr1,
    const float* __restrict__ u2_w, const float* __restrict__ u2_b,
    const float* __restrict__ ps2, const float* __restrict__ ph2, const float* __restrict__ wr2,
    const float* __restrict__ u3_w, const float* __restrict__ u3_b,
    const float* __restrict__ ps3, const float* __restrict__ ph3, const float* __restrict__ wr3,
    const float* __restrict__ u4_w, const float* __restrict__ u4_b,
    const float* __restrict__ ps4, const float* __restrict__ ph4, const float* __restrict__ wr4)
{
    __shared__ float Wl[144], Bl[12], part[4*144], Ml[144];
    const int tid  = threadIdx.x;
    const int lane = tid & 63;
    const int wvid = tid >> 6;
    float* __restrict__ xbat = xb + (size_t)blockIdx.x * (NPTS * 12);

#pragma unroll 1
    for (int r = 0; r < 4; ++r) {
        const float *wp, *bp, *pp, *hp, *rp;
        if      (r == 0) { wp=u1_w; bp=u1_b; pp=ps1; hp=ph1; rp=wr1; }
        else if (r == 1) { wp=u2_w; bp=u2_b; pp=ps2; hp=ph2; rp=wr2; }
        else if (r == 2) { wp=u3_w; bp=u3_b; pp=ps3; hp=ph3; rp=wr3; }
        else             { wp=u4_w; bp=u4_b; pp=ps4; hp=ph4; rp=wr4; }
        if (tid < 144) Wl[tid] = wp[tid];
        if (tid < 12)  Bl[tid] = bp[tid];
        const float sc = pp[0] * hp[0];
        const float wc = rp[0];
        __syncthreads();

        // ---- phase 1: per-thread partial M[12][12] over 8 owned rows
        float Mp[144];
#pragma unroll
        for (int k = 0; k < 144; ++k) Mp[k] = 0.f;
#pragma unroll 1
        for (int i = 0; i < 8; ++i) {
            const float* row = xbat + (i * 256 + tid) * 12;
            float xr[12];
#pragma unroll
            for (int d = 0; d < 12; ++d) xr[d] = row[d];
            float ur[12];
#pragma unroll
            for (int k = 0; k < 12; ++k) {
                float a = Bl[k];
#pragma unroll
                for (int d = 0; d < 12; ++d) a = fmaf(Wl[k*12+d], xr[d], a);
                ur[k] = fmaxf(a, 0.f);
            }
#pragma unroll
            for (int d = 0; d < 12; ++d)
#pragma unroll
                for (int e = 0; e < 12; ++e)
                    Mp[d*12+e] = fmaf(xr[d], ur[e], Mp[d*12+e]);
        }

        // ---- reduce M across 64 lanes, then across 4 waves via LDS
#pragma unroll
        for (int k = 0; k < 144; ++k) {
            float v = Mp[k];
            v += __shfl_down(v, 32);
            v += __shfl_down(v, 16);
            v += __shfl_down(v, 8);
            v += __shfl_down(v, 4);
            v += __shfl_down(v, 2);
            v += __shfl_down(v, 1);
            if (lane == 0) part[wvid * 144 + k] = v;
        }
        __syncthreads();
        if (tid < 144)
            Ml[tid] = part[tid] + part[144 + tid] + part[288 + tid] + part[432 + tid];
        __syncthreads();

        // ---- phase 2: f_i = coef*(x_i·M - ||x_i||^2 u_i) + x_i  (in place)
        const float coef = wc * sc * (1.f / (float)NPTS);
#pragma unroll 1
        for (int i = 0; i < 8; ++i) {
            float* row = xbat + (i * 256 + tid) * 12;
            float xr[12];
#pragma unroll
            for (int d = 0; d < 12; ++d) xr[d] = row[d];
            float ur[12];
#pragma unroll
            for (int k = 0; k < 12; ++k) {
                float a = Bl[k];
#pragma unroll
                for (int d = 0; d < 12; ++d) a = fmaf(Wl[k*12+d], xr[d], a);
                ur[k] = fmaxf(a, 0.f);
            }
            float xx = 0.f;
#pragma unroll
            for (int d = 0; d < 12; ++d) xx = fmaf(xr[d], xr[d], xx);
            float fo[12];
#pragma unroll
            for (int e = 0; e < 12; ++e) {
                float acc = 0.f;
#pragma unroll
                for (int d = 0; d < 12; ++d) acc = fmaf(xr[d], Ml[d*12+e], acc);
                fo[e] = fmaf(coef, acc - xx * ur[e], xr[e]);
            }
#pragma unroll
            for (int e = 0; e < 12; ++e) row[e] = fo[e];
        }
        __syncthreads();   // writes visible before next relmod's phase 1 reads
    }
}

// ---------------------------------------------------------------------------
// K3: r[16,2048,12] -> out[16,2048,3]
//   relu(bn4(fc4)) -> relu(fc5) -> [fc6 | fc7] concat
// ---------------------------------------------------------------------------
__global__ __launch_bounds__(256) void k3_head(
    const float* __restrict__ xb,
    const float* __restrict__ fc4_w, const float* __restrict__ fc4_b,
    const float* __restrict__ bn4_g, const float* __restrict__ bn4_b,
    const float* __restrict__ fc5_w, const float* __restrict__ fc5_b,
    const float* __restrict__ fc6_w, const float* __restrict__ fc6_b,
    const float* __restrict__ fc7_w, const float* __restrict__ fc7_b,
    float* __restrict__ out)
{
    __shared__ float w4[72], b4[6], w5[18], b5[3], w6[3], w7[6], bb[3];
    const int tid = threadIdx.x;
    if (tid < 72) w4[tid] = fc4_w[tid];
    if (tid < 6)  b4[tid] = fc4_b[tid];
    if (tid < 18) w5[tid] = fc5_w[tid];
    if (tid < 3)  { b5[tid] = fc5_b[tid]; w6[tid] = fc6_w[tid]; }
    if (tid < 6)  w7[tid] = fc7_w[tid];
    if (tid == 0) bb[0] = fc6_b[0];
    if (tid < 2)  bb[1 + tid] = fc7_b[tid];
    __syncthreads();

    const int n = blockIdx.x * 256 + tid;
    const float g4 = bn4_g[n], e4 = bn4_b[n];

    // ---- pass A: bn4 stats (96 values)
    float s = 0.f, q = 0.f;
    for (int b = 0; b < NB; ++b) {
        const float* row = xb + (b * NPTS + n) * 12;
#pragma unroll
        for (int c = 0; c < 6; ++c) {
            float h = b4[c];
#pragma unroll
            for (int d = 0; d < 12; ++d) h = fmaf(w4[c*12+d], row[d], h);
            s += h; q = fmaf(h, h, q);
        }
    }
    const float m  = s * (1.f/96.f);
    const float iv = 1.f / sqrtf(q*(1.f/96.f) - m*m + 1e-5f);

    // ---- pass B: apply + heads
    for (int b = 0; b < NB; ++b) {
        const float* row = xb + (b * NPTS + n) * 12;
        float a4[6];
#pragma unroll
        for (int c = 0; c < 6; ++c) {
            float h = b4[c];
#pragma unroll
            for (int d = 0; d < 12; ++d) h = fmaf(w4[c*12+d], row[d], h);
            a4[c] = fmaxf((h - m) * iv * g4 + e4, 0.f);
        }
        float a5[3];
#pragma unroll
        for (int c = 0; c < 3; ++c) {
            float h = b5[c];
#pragma unroll
            for (int d = 0; d < 6; ++d) h = fmaf(w5[c*6+d], a4[d], h);
            a5[c] = fmaxf(h, 0.f);
        }
        const float cls = fmaf(w6[0], a5[0], fmaf(w6[1], a5[1], fmaf(w6[2], a5[2], bb[0])));
        const float g0  = fmaf(w7[0], a5[0], fmaf(w7[1], a5[1], fmaf(w7[2], a5[2], bb[1])));
        const float g1v = fmaf(w7[3], a5[0], fmaf(w7[4], a5[1], fmaf(w7[5], a5[2], bb[2])));
        float* op = out + (b * NPTS + n) * 3;
        op[0] = cls; op[1] = g0; op[2] = g1v;
    }
}

// ---------------------------------------------------------------------------
extern "C" void kernel_launch(void* const* d_in, const int* in_sizes, int n_in,
                              void* d_out, int out_size, void* d_ws, size_t ws_size,
                              hipStream_t stream)
{
    const float* X = (const float*)d_in[0];
    float* enc = (float*)d_ws;   // [16,2048,12] fp32 = 1.5 MB scratch

    k1_encode<<<NPTS/256, 256, 0, stream>>>(
        X,
        (const float*)d_in[1],  (const float*)d_in[2],   // fc1
        (const float*)d_in[3],  (const float*)d_in[4],   // bn1
        (const float*)d_in[5],  (const float*)d_in[6],   // fc2
        (const float*)d_in[7],  (const float*)d_in[8],   // bn2
        (const float*)d_in[9],  (const float*)d_in[10],  // fc3
        enc);

    k2_relmod<<<NB, 256, 0, stream>>>(
        enc,
        (const float*)d_in[11], (const float*)d_in[12], (const float*)d_in[13],
        (const float*)d_in[14], (const float*)d_in[15],
        (const float*)d_in[16], (const float*)d_in[17], (const float*)d_in[18],
        (const float*)d_in[19], (const float*)d_in[20],
        (const float*)d_in[21], (const float*)d_in[22], (const float*)d_in[23],
        (const float*)d_in[24], (const float*)d_in[25],
        (const float*)d_in[26], (const float*)d_in[27], (const float*)d_in[28],
        (const float*)d_in[29], (const float*)d_in[30]);

    k3_head<<<NPTS/256, 256, 0, stream>>>(
        enc,
        (const float*)d_in[31], (const float*)d_in[32],  // fc4
        (const float*)d_in[33], (const float*)d_in[34],  // bn4
        (const float*)d_in[35], (const float*)d_in[36],  // fc5
        (const float*)d_in[37], (const float*)d_in[38],  // fc6
        (const float*)d_in[39], (const float*)d_in[40],  // fc7
        (float*)d_out);
}

// Round 2
// 170.127 us; speedup vs baseline: 3.1168x; 3.1168x over previous
//
#include <hip/hip_runtime.h>
#include <math.h>

#define NB    16
#define NPTS  2048
#define DDIM  12
#define CHUNK 128
#define NCH   16      // NPTS / CHUNK
#define LPAD  132     // CHUNK + 4 : LDS transpose row pitch (bank-conflict-free)

// ---------------------------------------------------------------------------
// K1: x[16,2048,3] -> enc[16,2048,12], single pass.
// thread = (b, n): b = tid & 15 (lane-local group), nl = tid >> 4.
// BN stats over (b,c) via 16-lane __shfl_xor butterflies.
// ---------------------------------------------------------------------------
__global__ __launch_bounds__(128) void k1_encode(
    const float* __restrict__ x,
    const float* __restrict__ fc1_w, const float* __restrict__ fc1_b,
    const float* __restrict__ bn1_g, const float* __restrict__ bn1_b,
    const float* __restrict__ fc2_w, const float* __restrict__ fc2_b,
    const float* __restrict__ bn2_g, const float* __restrict__ bn2_b,
    const float* __restrict__ fc3_w, const float* __restrict__ fc3_b,
    float* __restrict__ enc)
{
    __shared__ float w1[18], b1[6], w2[72], b2[12], w3[144], b3[12];
    const int tid = threadIdx.x;
    for (int k = tid; k < 144; k += 128) w3[k] = fc3_w[k];
    if (tid < 18) w1[tid] = fc1_w[tid];
    if (tid < 6)  b1[tid] = fc1_b[tid];
    if (tid < 72) w2[tid] = fc2_w[tid];
    if (tid < 12) { b2[tid] = fc2_b[tid]; b3[tid] = fc3_b[tid]; }
    __syncthreads();

    const int b  = tid & 15;
    const int nl = tid >> 4;
    const int n  = blockIdx.x * 8 + nl;

    const float* xp = x + (b * NPTS + n) * 3;
    const float x0 = xp[0], x1 = xp[1], x2 = xp[2];

    // fc1 + bn1 stats (over b,c : 96 vals)
    float h1[6];
    float s = 0.f, q = 0.f;
#pragma unroll
    for (int c = 0; c < 6; ++c) {
        float h = fmaf(w1[c*3+0], x0, fmaf(w1[c*3+1], x1, fmaf(w1[c*3+2], x2, b1[c])));
        h1[c] = h; s += h; q = fmaf(h, h, q);
    }
#pragma unroll
    for (int m = 1; m <= 8; m <<= 1) { s += __shfl_xor(s, m); q += __shfl_xor(q, m); }
    const float m1 = s * (1.f/96.f);
    const float i1 = 1.f / sqrtf(q*(1.f/96.f) - m1*m1 + 1e-5f);
    const float g1 = bn1_g[n], e1 = bn1_b[n];
    float a1[6];
#pragma unroll
    for (int c = 0; c < 6; ++c) a1[c] = fmaxf((h1[c] - m1) * i1 * g1 + e1, 0.f);

    // fc2 + bn2 stats (192 vals)
    float h2[12];
    s = 0.f; q = 0.f;
#pragma unroll
    for (int c = 0; c < 12; ++c) {
        float h = b2[c];
#pragma unroll
        for (int d = 0; d < 6; ++d) h = fmaf(w2[c*6+d], a1[d], h);
        h2[c] = h; s += h; q = fmaf(h, h, q);
    }
#pragma unroll
    for (int m = 1; m <= 8; m <<= 1) { s += __shfl_xor(s, m); q += __shfl_xor(q, m); }
    const float m2 = s * (1.f/192.f);
    const float i2 = 1.f / sqrtf(q*(1.f/192.f) - m2*m2 + 1e-5f);
    const float g2 = bn2_g[n], e2 = bn2_b[n];
    float a2[12];
#pragma unroll
    for (int c = 0; c < 12; ++c) a2[c] = fmaxf((h2[c] - m2) * i2 * g2 + e2, 0.f);

    // fc3 + sigmoid -> enc
    float* ep = enc + (b * NPTS + n) * DDIM;
#pragma unroll
    for (int c = 0; c < 12; ++c) {
        float h = b3[c];
#pragma unroll
        for (int d = 0; d < 12; ++d) h = fmaf(w3[c*12+d], a2[d], h);
        ep[c] = 1.f / (1.f + expf(-h));
    }
}

// ---------------------------------------------------------------------------
// Shared device helper: LDS-transpose M-partial reduce.
// threads < CHUNK wrote xT/uT; threads < 144 each produce one M[d][e] partial.
// ---------------------------------------------------------------------------
__device__ __forceinline__ void reduce_partial(
    const float* xT, const float* uT, int tid, float* __restrict__ Pout, int bidx)
{
    if (tid < 144) {
        const int d = tid / 12;
        const int e = tid - d * 12;
        const float4* xp = (const float4*)(xT + d * LPAD);
        const float4* up = (const float4*)(uT + e * LPAD);
        float m = 0.f;
#pragma unroll
        for (int r = 0; r < CHUNK/4; ++r) {
            float4 a = xp[r], c = up[r];
            m = fmaf(a.x, c.x, m); m = fmaf(a.y, c.y, m);
            m = fmaf(a.z, c.z, m); m = fmaf(a.w, c.w, m);
        }
        Pout[bidx * 144 + tid] = m;
    }
}

// ---------------------------------------------------------------------------
// KR: M1 partials. block = (batch, chunk), 256 threads (128 own rows).
// ---------------------------------------------------------------------------
__global__ __launch_bounds__(256) void k_reduce(
    const float* __restrict__ xb,
    const float* __restrict__ uw, const float* __restrict__ ub,
    float* __restrict__ Pout)
{
    __shared__ float W[144], B[12];
    __shared__ float xT[DDIM * LPAD], uT[DDIM * LPAD];
    const int tid = threadIdx.x;
    const int batch = blockIdx.x >> 4, ch = blockIdx.x & 15;
    for (int k = tid; k < 144; k += 256) W[k] = uw[k];
    if (tid < 12) B[tid] = ub[tid];
    __syncthreads();

    if (tid < CHUNK) {
        const float* row = xb + ((batch * NPTS) + ch * CHUNK + tid) * DDIM;
        float xr[12];
#pragma unroll
        for (int d = 0; d < 12; ++d) xr[d] = row[d];
#pragma unroll
        for (int k = 0; k < 12; ++k) {
            float a = B[k];
#pragma unroll
            for (int d = 0; d < 12; ++d) a = fmaf(W[k*12+d], xr[d], a);
            uT[k * LPAD + tid] = fmaxf(a, 0.f);
            xT[k * LPAD + tid] = xr[k];
        }
    }
    __syncthreads();
    reduce_partial(xT, uT, tid, Pout, blockIdx.x);
}

// ---------------------------------------------------------------------------
// KA: apply relmod r (using Pin -> M) in place, then produce partials of
// M_{r+1} from the NEW rows (registers). block = (batch, chunk).
// ---------------------------------------------------------------------------
__global__ __launch_bounds__(256) void k_apply_reduce(
    float* __restrict__ xb,
    const float* __restrict__ Pin, float* __restrict__ Pout,
    const float* __restrict__ wc, const float* __restrict__ bc,
    const float* __restrict__ ps, const float* __restrict__ ph, const float* __restrict__ wr,
    const float* __restrict__ wn, const float* __restrict__ bn)
{
    __shared__ float Wc[144], Bc[12], Wn[144], Bn[12], Ml[144];
    __shared__ float xT[DDIM * LPAD], uT[DDIM * LPAD];
    const int tid = threadIdx.x;
    const int batch = blockIdx.x >> 4, ch = blockIdx.x & 15;
    for (int k = tid; k < 144; k += 256) { Wc[k] = wc[k]; Wn[k] = wn[k]; }
    if (tid < 12) { Bc[tid] = bc[tid]; Bn[tid] = bn[tid]; }
    if (tid < 144) {
        float sm = 0.f;
#pragma unroll
        for (int c = 0; c < NCH; ++c) sm += Pin[(batch * NCH + c) * 144 + tid];
        Ml[tid] = sm;
    }
    __syncthreads();

    const float coef = wr[0] * ps[0] * ph[0] * (1.f / (float)NPTS);
    if (tid < CHUNK) {
        float* rowp = xb + ((batch * NPTS) + ch * CHUNK + tid) * DDIM;
        float xr[12];
#pragma unroll
        for (int d = 0; d < 12; ++d) xr[d] = rowp[d];
        float uc[12];
#pragma unroll
        for (int k = 0; k < 12; ++k) {
            float a = Bc[k];
#pragma unroll
            for (int d = 0; d < 12; ++d) a = fmaf(Wc[k*12+d], xr[d], a);
            uc[k] = fmaxf(a, 0.f);
        }
        float xx = 0.f;
#pragma unroll
        for (int d = 0; d < 12; ++d) xx = fmaf(xr[d], xr[d], xx);
        float fo[12];
#pragma unroll
        for (int e = 0; e < 12; ++e) {
            float acc = 0.f;
#pragma unroll
            for (int d = 0; d < 12; ++d) acc = fmaf(xr[d], Ml[d*12+e], acc);
            fo[e] = fmaf(coef, fmaf(-xx, uc[e], acc), xr[e]);
        }
#pragma unroll
        for (int e = 0; e < 12; ++e) rowp[e] = fo[e];
        // next relmod's unary on the new row
#pragma unroll
        for (int k = 0; k < 12; ++k) {
            float a = Bn[k];
#pragma unroll
            for (int d = 0; d < 12; ++d) a = fmaf(Wn[k*12+d], fo[d], a);
            uT[k * LPAD + tid] = fmaxf(a, 0.f);
            xT[k * LPAD + tid] = fo[k];
        }
    }
    __syncthreads();
    reduce_partial(xT, uT, tid, Pout, blockIdx.x);
}

// ---------------------------------------------------------------------------
// K3: apply relmod4 (per-row, M4 from partials) + fc4/bn4/relu + fc5/relu +
// heads. thread = (b, n) like K1.
// ---------------------------------------------------------------------------
__global__ __launch_bounds__(128) void k3_head(
    const float* __restrict__ xb, const float* __restrict__ P4,
    const float* __restrict__ u4w, const float* __restrict__ u4b,
    const float* __restrict__ ps4, const float* __restrict__ ph4, const float* __restrict__ wr4,
    const float* __restrict__ fc4_w, const float* __restrict__ fc4_b,
    const float* __restrict__ bn4_g, const float* __restrict__ bn4_b,
    const float* __restrict__ fc5_w, const float* __restrict__ fc5_b,
    const float* __restrict__ fc6_w, const float* __restrict__ fc6_b,
    const float* __restrict__ fc7_w, const float* __restrict__ fc7_b,
    float* __restrict__ out)
{
    __shared__ float W4[144], B4[12], M4[NB * 144];
    __shared__ float w4[72], b4[6], w5[18], b5[3], w6[3], w7[6], bb[3];
    const int tid = threadIdx.x;
    for (int k = tid; k < 144; k += 128) W4[k] = u4w[k];
    if (tid < 12) B4[tid] = u4b[tid];
    for (int k = tid; k < NB * 144; k += 128) {
        const int bt = k / 144, ix = k - bt * 144;
        float sm = 0.f;
#pragma unroll
        for (int c = 0; c < NCH; ++c) sm += P4[(bt * NCH + c) * 144 + ix];
        M4[k] = sm;
    }
    if (tid < 72) w4[tid] = fc4_w[tid];
    if (tid < 6)  b4[tid] = fc4_b[tid];
    if (tid < 18) w5[tid] = fc5_w[tid];
    if (tid < 3)  { b5[tid] = fc5_b[tid]; w6[tid] = fc6_w[tid]; }
    if (tid < 6)  w7[tid] = fc7_w[tid];
    if (tid == 0) bb[0] = fc6_b[0];
    if (tid < 2)  bb[1 + tid] = fc7_b[tid];
    __syncthreads();

    const int b  = tid & 15;
    const int nl = tid >> 4;
    const int n  = blockIdx.x * 8 + nl;
    const float coef = wr4[0] * ps4[0] * ph4[0] * (1.f / (float)NPTS);

    const float* rowp = xb + (b * NPTS + n) * DDIM;
    float xr[12];
#pragma unroll
    for (int d = 0; d < 12; ++d) xr[d] = rowp[d];
    float uc[12];
#pragma unroll
    for (int k = 0; k < 12; ++k) {
        float a = B4[k];
#pragma unroll
        for (int d = 0; d < 12; ++d) a = fmaf(W4[k*12+d], xr[d], a);
        uc[k] = fmaxf(a, 0.f);
    }
    float xx = 0.f;
#pragma unroll
    for (int d = 0; d < 12; ++d) xx = fmaf(xr[d], xr[d], xx);
    const float* Mb = M4 + b * 144;
    float r4[12];
#pragma unroll
    for (int e = 0; e < 12; ++e) {
        float acc = 0.f;
#pragma unroll
        for (int d = 0; d < 12; ++d) acc = fmaf(xr[d], Mb[d*12+e], acc);
        r4[e] = fmaf(coef, fmaf(-xx, uc[e], acc), xr[e]);
    }

    // fc4 + bn4 stats (96 vals over b,c)
    float h4[6];
    float s = 0.f, q = 0.f;
#pragma unroll
    for (int c = 0; c < 6; ++c) {
        float h = b4[c];
#pragma unroll
        for (int d = 0; d < 12; ++d) h = fmaf(w4[c*12+d], r4[d], h);
        h4[c] = h; s += h; q = fmaf(h, h, q);
    }
#pragma unroll
    for (int m = 1; m <= 8; m <<= 1) { s += __shfl_xor(s, m); q += __shfl_xor(q, m); }
    const float mm = s * (1.f/96.f);
    const float iv = 1.f / sqrtf(q*(1.f/96.f) - mm*mm + 1e-5f);
    const float g4 = bn4_g[n], e4 = bn4_b[n];
    float a4[6];
#pragma unroll
    for (int c = 0; c < 6; ++c) a4[c] = fmaxf((h4[c] - mm) * iv * g4 + e4, 0.f);

    float a5[3];
#pragma unroll
    for (int c = 0; c < 3; ++c) {
        float h = b5[c];
#pragma unroll
        for (int d = 0; d < 6; ++d) h = fmaf(w5[c*6+d], a4[d], h);
        a5[c] = fmaxf(h, 0.f);
    }
    const float cls = fmaf(w6[0], a5[0], fmaf(w6[1], a5[1], fmaf(w6[2], a5[2], bb[0])));
    const float g0  = fmaf(w7[0], a5[0], fmaf(w7[1], a5[1], fmaf(w7[2], a5[2], bb[1])));
    const float g1v = fmaf(w7[3], a5[0], fmaf(w7[4], a5[1], fmaf(w7[5], a5[2], bb[2])));
    float* op = out + (b * NPTS + n) * 3;
    op[0] = cls; op[1] = g0; op[2] = g1v;
}

// ---------------------------------------------------------------------------
extern "C" void kernel_launch(void* const* d_in, const int* in_sizes, int n_in,
                              void* d_out, int out_size, void* d_ws, size_t ws_size,
                              hipStream_t stream)
{
    const float* X = (const float*)d_in[0];
    float* enc = (float*)d_ws;                              // [16,2048,12] = 1.5 MB
    float* Pa  = enc + NB * NPTS * DDIM;                    // [16,16,144] = 144 KB
    float* Pb  = Pa + NB * NCH * 144;                       // [16,16,144]

    k1_encode<<<NPTS/8, 128, 0, stream>>>(
        X,
        (const float*)d_in[1],  (const float*)d_in[2],
        (const float*)d_in[3],  (const float*)d_in[4],
        (const float*)d_in[5],  (const float*)d_in[6],
        (const float*)d_in[7],  (const float*)d_in[8],
        (const float*)d_in[9],  (const float*)d_in[10],
        enc);

    k_reduce<<<NB*NCH, 256, 0, stream>>>(
        enc, (const float*)d_in[11], (const float*)d_in[12], Pa);

    k_apply_reduce<<<NB*NCH, 256, 0, stream>>>(
        enc, Pa, Pb,
        (const float*)d_in[11], (const float*)d_in[12],
        (const float*)d_in[13], (const float*)d_in[14], (const float*)d_in[15],
        (const float*)d_in[16], (const float*)d_in[17]);

    k_apply_reduce<<<NB*NCH, 256, 0, stream>>>(
        enc, Pb, Pa,
        (const float*)d_in[16], (const float*)d_in[17],
        (const float*)d_in[18], (const float*)d_in[19], (const float*)d_in[20],
        (const float*)d_in[21], (const float*)d_in[22]);

    k_apply_reduce<<<NB*NCH, 256, 0, stream>>>(
        enc, Pa, Pb,
        (const float*)d_in[21], (const float*)d_in[22],
        (const float*)d_in[23], (const float*)d_in[24], (const float*)d_in[25],
        (const float*)d_in[26], (const float*)d_in[27]);

    k3_head<<<NPTS/8, 128, 0, stream>>>(
        enc, Pb,
        (const float*)d_in[26], (const float*)d_in[27],
        (const float*)d_in[28], (const float*)d_in[29], (const float*)d_in[30],
        (const float*)d_in[31], (const float*)d_in[32],
        (const float*)d_in[33], (const float*)d_in[34],
        (const float*)d_in[35], (const float*)d_in[36],
        (const float*)d_in[37], (const float*)d_in[38],
        (const float*)d_in[39], (const float*)d_in[40],
        (float*)d_out);
}